// Round 5
// baseline (261.593 us; speedup 1.0000x reference)
//
#include <hip/hip_runtime.h>
#include <math.h>

#define NH   8
#define PP   3
#define HP   24      // NH*PP
#define E    512
#define EK   64
#define D    128
#define LL   2048
#define BB   64
#define TT   1024
#define LAT  256
#define HID  512
#define CH   8       // l-chunks in weighted-sum pass
#define CL   256     // chunk length

typedef __attribute__((ext_vector_type(8))) short bf16x8;
typedef __attribute__((ext_vector_type(4))) float f32x4;
typedef __attribute__((ext_vector_type(16))) float f32x16;

// ---- workspace offsets (in floats) ----
#define OFF_Q      ((size_t)0)            // 1536
#define OFF_VS     ((size_t)2048)         // 1536 (vsin 24x64)
#define OFF_WA     ((size_t)4096)         // 24
#define OFF_WB     ((size_t)4128)         // 24
#define OFF_SB     ((size_t)4160)         // 24
#define OFF_CV     ((size_t)4224)         // 256
#define OFF_PMAX   ((size_t)4608)         // 12288 (64 x 8 x 24)
#define OFF_COEF   ((size_t)24576)        // 49152
#define OFF_CVP    ((size_t)73728)        // 8192 (cvec partials)
#define OFF_P2     ((size_t)81920)        // 393216 (part2; abuf overlays after k_cred)
#define OFF_A      ((size_t)81920)        // 98304  (abuf, overlays part2)
#define OFF_PART   ((size_t)475136)       // 3145728 (part)
#define OFF_SC     ((size_t)3620864)      // 3145728 (scores; W2F/W3F overlay after k_wsum)

__device__ inline ushort f2bf(float x) {
    union { float f; uint u; } v; v.f = x;
    uint r = v.u + 0x7fffu + ((v.u >> 16) & 1u);
    return (ushort)(r >> 16);
}
__device__ inline uint swzA(uint a) { return a ^ (((a >> 10) & 7u) << 4); }  // 1024B rows
__device__ inline uint swzB(uint a) { return a ^ (((a >> 8) & 7u) << 4); }   // 256B rows
__device__ inline uint pk2(float lo, float hi) {
    return (uint)f2bf(lo) | ((uint)f2bf(hi) << 16);
}
__device__ inline float h1f(float a0, float a1, float a2, float t) {
    return fmaxf(fmaf(t, fmaf(t, a2, a1), a0), 0.f);
}

// K1: q[p][e] = query[p]@W_q + b_q   (batch-independent)
__global__ __launch_bounds__(512) void k_q(const float* __restrict__ query,
                                           const float* __restrict__ W_q,
                                           const float* __restrict__ b_q,
                                           float* __restrict__ qbuf) {
    int p = blockIdx.x, e = threadIdx.x;
    float acc = b_q[e];
    for (int i = 0; i < E; ++i) acc += query[p * E + i] * W_q[(size_t)i * E + e];
    qbuf[p * E + e] = acc;
}

// K2: per (hp): v[e] = (1/8)*sum_j W_k[e][h*64+j] q[p][..]; emit vsin (e%8==0 cols),
//     wA = sum v*w_te, wB = sum v*b_te, sbias.
__global__ __launch_bounds__(512) void k_v(const float* __restrict__ W_k,
                                           const float* __restrict__ b_k,
                                           const float* __restrict__ qbuf,
                                           const float* __restrict__ w_te,
                                           const float* __restrict__ b_te,
                                           float* __restrict__ vsin,
                                           float* __restrict__ wA,
                                           float* __restrict__ wB,
                                           float* __restrict__ sbias) {
    int hp = blockIdx.x;
    int h = hp / PP, p = hp % PP;
    int e = threadIdx.x;
    const float scale = 0.125f;  // 1/sqrt(64)
    float acc = 0.f;
    for (int j = 0; j < EK; ++j)
        acc += W_k[(size_t)e * E + h * EK + j] * qbuf[p * E + h * EK + j];
    float v = acc * scale;
    if ((e & 7) == 0) vsin[hp * 64 + (e >> 3)] = v;
    __shared__ float r1[512], r2[512];
    r1[e] = v * w_te[e];
    r2[e] = v * b_te[e];
    __syncthreads();
    for (int s = 256; s > 0; s >>= 1) {
        if (e < s) { r1[e] += r1[e + s]; r2[e] += r2[e + s]; }
        __syncthreads();
    }
    if (e == 0) {
        wA[hp] = r1[0];
        wB[hp] = r2[0];
        float sb = 0.f;
        for (int j = 0; j < EK; ++j) sb += b_k[h * EK + j] * qbuf[p * E + h * EK + j];
        sbias[hp] = sb * scale;
    }
}

// K2b: parallel Cvec partials: cvp[h*4+cc][o] = sum_{c in chunk} W_o[h*256+128+c][o]
__global__ __launch_bounds__(256) void k_cvp(const float* __restrict__ W_o,
                                             float* __restrict__ cvp) {
    int h = blockIdx.x, cc = blockIdx.y, o = threadIdx.x;
    float acc = 0.f;
    #pragma unroll 8
    for (int c = cc * 32; c < cc * 32 + 32; ++c)
        acc += W_o[(size_t)(h * 256 + 128 + c) * LAT + o];
    cvp[(h * 4 + cc) * LAT + o] = acc;
}

// K2c: Cvec[o] = b_o[o] + sum_32 cvp
__global__ __launch_bounds__(256) void k_cvr(const float* __restrict__ cvp,
                                             const float* __restrict__ b_o,
                                             float* __restrict__ Cvec) {
    int o = threadIdx.x;
    float acc = b_o[o];
    #pragma unroll
    for (int i = 0; i < 32; ++i) acc += cvp[i * LAT + o];
    Cvec[o] = acc;
}

// K3: scores[b][hp][l] = ts*wA[hp] + wB[hp] + sb[hp] + sum_j (sin(kj)-kj)*vsin[hp][j]
//     + per-(b,seg) partial max -> pmax
__global__ __launch_bounds__(256) void k_scores(const float* __restrict__ timesteps,
                                                const float* __restrict__ w_te,
                                                const float* __restrict__ b_te,
                                                const float* __restrict__ vsin,
                                                const float* __restrict__ wA,
                                                const float* __restrict__ wB,
                                                const float* __restrict__ sb,
                                                float* __restrict__ scores,
                                                float* __restrict__ pmax) {
    __shared__ float vs_s[HP * 64];   // 6 KB
    __shared__ float w8_s[64], b8_s[64];
    __shared__ float wA_s[HP], wB_s[HP], sb_s[HP];
    __shared__ float wmax_s[HP][4];
    int tid = threadIdx.x;
    for (int i = tid; i < HP * 64; i += 256) vs_s[i] = vsin[i];
    if (tid < 64) { w8_s[tid] = w_te[tid * 8]; b8_s[tid] = b_te[tid * 8]; }
    if (tid < HP) { wA_s[tid] = wA[tid]; wB_s[tid] = wB[tid]; sb_s[tid] = sb[tid]; }
    __syncthreads();

    int b = blockIdx.x >> 3, seg = blockIdx.x & 7;
    int l = seg * 256 + tid;
    float ts = timesteps[(size_t)b * LL + l];

    float dj[64];
    #pragma unroll
    for (int j = 0; j < 64; ++j) {
        float kj = fmaf(ts, w8_s[j], b8_s[j]);
        dj[j] = __sinf(kj) - kj;
    }

    int wid = tid >> 6, lane = tid & 63;
    for (int hp = 0; hp < HP; ++hp) {
        float acc = fmaf(ts, wA_s[hp], wB_s[hp]) + sb_s[hp];
        #pragma unroll
        for (int j0 = 0; j0 < 64; j0 += 4) {
            float4 v4 = *(const float4*)&vs_s[hp * 64 + j0];
            acc += dj[j0] * v4.x + dj[j0 + 1] * v4.y + dj[j0 + 2] * v4.z + dj[j0 + 3] * v4.w;
        }
        scores[((size_t)b * HP + hp) * LL + l] = acc;
        float m = acc;
        #pragma unroll
        for (int off = 32; off > 0; off >>= 1) m = fmaxf(m, __shfl_xor(m, off));
        if (lane == 0) wmax_s[hp][wid] = m;
    }
    __syncthreads();
    if (tid < HP)
        pmax[((size_t)b * 8 + seg) * HP + tid] =
            fmaxf(fmaxf(wmax_s[tid][0], wmax_s[tid][1]), fmaxf(wmax_s[tid][2], wmax_s[tid][3]));
}

// K5: per-chunk partial weighted sums: part[b][ch][hp][0:128]=num, [128:256]=den
__global__ __launch_bounds__(256) void k_wsum(const float* __restrict__ scores,
                                              const float* __restrict__ pmax,
                                              const float* __restrict__ X,
                                              const float* __restrict__ M,
                                              float* __restrict__ part) {
    int b = blockIdx.x / CH, ch = blockIdx.x % CH;
    int l0 = ch * CL, tid = threadIdx.x;
    __shared__ float m_s[HP];
    __shared__ float w_s[HP][CL];   // 24 KB
    if (tid < HP) {
        float m = -INFINITY;
        for (int s = 0; s < 8; ++s) m = fmaxf(m, pmax[((size_t)b * 8 + s) * HP + tid]);
        m_s[tid] = m;
    }
    __syncthreads();
    for (int i = tid; i < HP * CL; i += 256) {
        int hp = i / CL, lc = i % CL;
        w_s[hp][lc] = __expf(scores[((size_t)b * HP + hp) * LL + l0 + lc] - m_s[hp]);
    }
    __syncthreads();

    int c = tid & 127;
    int hh = tid >> 7;   // hp half: 12*hh .. 12*hh+11
    float accn[12], accd[12];
    #pragma unroll
    for (int i = 0; i < 12; ++i) { accn[i] = 0.f; accd[i] = 0.f; }

    for (int lc = 0; lc < CL; lc += 4) {
        float mv[4], xv[4];
        #pragma unroll
        for (int j = 0; j < 4; ++j) {
            size_t l = (size_t)b * LL + l0 + lc + j;
            mv[j] = M[l * D + c];
            xv[j] = X[l * D + c] * mv[j];
        }
        #pragma unroll
        for (int i = 0; i < 12; ++i) {
            const float4 w4 = *(const float4*)&w_s[12 * hh + i][lc];
            accn[i] += w4.x * xv[0] + w4.y * xv[1] + w4.z * xv[2] + w4.w * xv[3];
            accd[i] += w4.x * mv[0] + w4.y * mv[1] + w4.z * mv[2] + w4.w * mv[3];
        }
    }
    #pragma unroll
    for (int i = 0; i < 12; ++i) {
        int hp = 12 * hh + i;
        size_t base = ((size_t)(b * CH + ch) * HP + hp) * 256;
        part[base + c]       = accn[i];
        part[base + 128 + c] = accd[i];
    }
}

// K6a: per (b,h): ratio = num/den (with inline chunk reduce), partial W_o matmul
__global__ __launch_bounds__(256) void k_coefp(const float* __restrict__ part,
                                               const float* __restrict__ W_o,
                                               float* __restrict__ part2) {
    int b = blockIdx.x, h = blockIdx.y;
    int tid = threadIdx.x;
    __shared__ float ratio[PP][D];   // 1.5 KB
    for (int ii = tid; ii < PP * D; ii += 256) {
        int p = ii >> 7, c = ii & 127;
        int hp = h * PP + p;
        float n = 0.f, d = 0.f;
        for (int ch = 0; ch < CH; ++ch) {
            size_t base = ((size_t)(b * CH + ch) * HP + hp) * 256;
            n += part[base + c];
            d += part[base + 128 + c];
        }
        ratio[p][c] = n / d;
    }
    __syncthreads();
    int o = tid;
    float a0 = 0.f, a1 = 0.f, a2 = 0.f;
    #pragma unroll 4
    for (int c = 0; c < D; ++c) {
        float w = W_o[(size_t)(h * 256 + c) * LAT + o];
        a0 = fmaf(ratio[0][c], w, a0);
        a1 = fmaf(ratio[1][c], w, a1);
        a2 = fmaf(ratio[2][c], w, a2);
    }
    size_t base = (((size_t)b * NH + h) * PP) * LAT + o;
    part2[base]           = a0;
    part2[base + LAT]     = a1;
    part2[base + 2 * LAT] = a2;
}

// K6b: coeffs[b][p][o] = Cvec[o] + sum_h part2[b][h][p][o]
__global__ __launch_bounds__(256) void k_cred(const float* __restrict__ part2,
                                              const float* __restrict__ Cvec,
                                              float* __restrict__ coeffs) {
    int b = blockIdx.x, o = threadIdx.x;
    float cv = Cvec[o];
    for (int p = 0; p < PP; ++p) {
        float s = cv;
        for (int h = 0; h < NH; ++h)
            s += part2[(((size_t)b * NH + h) * PP + p) * LAT + o];
        coeffs[((size_t)b * PP + p) * LAT + o] = s;
    }
}

// K5c: build 32x32x16 fragment-major bf16 weights.
// W2F frag F = ks*16+JT (ks 0..31, JT 0..15): lane l elem e = W2[ks*16+8*(l>>5)+e][JT*32+(l&31)]
// W3F frag F2 = KT*4+CT (KT 0..31, CT 0..3):  lane l elem e = W3[KT*16+8*(l>>5)+e][CT*32+(l&31)]
__global__ __launch_bounds__(256) void k_cvt(const float* __restrict__ W2,
                                             const float* __restrict__ W3,
                                             ushort* __restrict__ W2F,
                                             ushort* __restrict__ W3F) {
    int gid = blockIdx.x * 256 + threadIdx.x;
    int l = gid & 63;
    int kb = 8 * (l >> 5);
    int cb = l & 31;
    if (gid < 32768) {
        int F = gid >> 6;           // 0..511
        int JT = F & 15, ks = F >> 4;
        int k0 = ks * 16 + kb, j = JT * 32 + cb;
        #pragma unroll
        for (int e = 0; e < 8; ++e)
            W2F[(size_t)gid * 8 + e] = f2bf(W2[(size_t)(k0 + e) * HID + j]);
    } else if (gid < 40960) {
        int g2 = gid - 32768;       // 0..8191
        int F2 = g2 >> 6;           // 0..127
        int CT = F2 & 3, KT = F2 >> 2;
        int k0 = KT * 16 + kb, c = CT * 32 + cb;
        #pragma unroll
        for (int e = 0; e < 8; ++e)
            W3F[(size_t)g2 * 8 + e] = f2bf(W3[(size_t)(k0 + e) * D + c]);
    }
}

// K7: a[b][i][j] = coeffs[b][i]@W1[:,j] (+ b1 for i==0); one block per b reads W1 once
__global__ __launch_bounds__(512) void k_avec3(const float* __restrict__ coeffs,
                                               const float* __restrict__ W1,
                                               const float* __restrict__ b1,
                                               float* __restrict__ abuf) {
    int b = blockIdx.x, j = threadIdx.x;
    const float* cf = coeffs + (size_t)b * PP * LAT;
    float a0 = b1[j], a1 = 0.f, a2 = 0.f;
    #pragma unroll 4
    for (int k = 0; k < LAT; ++k) {
        float w = W1[(size_t)k * HID + j];
        a0 = fmaf(cf[k], w, a0);
        a1 = fmaf(cf[LAT + k], w, a1);
        a2 = fmaf(cf[2 * LAT + k], w, a2);
    }
    abuf[(size_t)b * 3 * HID + j] = a0;
    abuf[(size_t)b * 3 * HID + HID + j] = a1;
    abuf[(size_t)b * 3 * HID + 2 * HID + j] = a2;
}

// K8: fused MFMA MLP, 32x32x16 path. 64 rows/block, 512 thr (8 waves).
// LDS: h1 [64][512] bf16 (64 KB, swzA) staged ONCE + h2q [64][128] bf16 (16 KB, swzB).
// jq loop (4 quarters of j): GEMM1 (operand-swapped, D1[j][r]) -> h2q -> GEMM2 partial.
__global__ __launch_bounds__(512, 2) void k_mlp5(const float* __restrict__ abuf,
                                                 const float* __restrict__ yts,
                                                 const ushort* __restrict__ W2F,
                                                 const float* __restrict__ b2,
                                                 const ushort* __restrict__ W3F,
                                                 const float* __restrict__ b3,
                                                 float* __restrict__ out) {
    __shared__ char lds[81920];
    char* H1 = lds;            // 65536 B
    char* H2 = lds + 65536;    // 16384 B
    int b = blockIdx.x, t0 = blockIdx.y * 64, tid = threadIdx.x;
    const float* a0p = abuf + (size_t)b * 3 * HID;
    const float* a1p = a0p + HID;
    const float* a2p = a1p + HID;

    // phase A (once): h1 = relu(a0 + t*a1 + t^2*a2) -> bf16 LDS [64 r][512 k], swzA
    {
        int r = tid >> 3, q = tid & 7;
        float t = yts[(size_t)b * TT + t0 + r];
        const float* A0 = a0p + q * 64;
        const float* A1 = a1p + q * 64;
        const float* A2 = a2p + q * 64;
        #pragma unroll
        for (int i = 0; i < 8; ++i) {
            float4 x0a = *(const float4*)(A0 + i * 8);
            float4 x0b = *(const float4*)(A0 + i * 8 + 4);
            float4 x1a = *(const float4*)(A1 + i * 8);
            float4 x1b = *(const float4*)(A1 + i * 8 + 4);
            float4 x2a = *(const float4*)(A2 + i * 8);
            float4 x2b = *(const float4*)(A2 + i * 8 + 4);
            uint4 pk;
            pk.x = pk2(h1f(x0a.x, x1a.x, x2a.x, t), h1f(x0a.y, x1a.y, x2a.y, t));
            pk.y = pk2(h1f(x0a.z, x1a.z, x2a.z, t), h1f(x0a.w, x1a.w, x2a.w, t));
            pk.z = pk2(h1f(x0b.x, x1b.x, x2b.x, t), h1f(x0b.y, x1b.y, x2b.y, t));
            pk.w = pk2(h1f(x0b.z, x1b.z, x2b.z, t), h1f(x0b.w, x1b.w, x2b.w, t));
            *(uint4*)(H1 + swzA((uint)(r * 1024 + q * 128 + i * 16))) = pk;
        }
    }
    __syncthreads();

    int lane = tid & 63, wj = tid >> 6;
    int l31 = lane & 31, hl = lane >> 5;
    int wlo = wj & 3, whi = wj >> 2;   // GEMM1: (jt=wlo, rc=whi); GEMM2: (ct=wlo, rh=whi)

    f32x16 acc2;
    {
        float bv = b3[wlo * 32 + l31];
        #pragma unroll
        for (int e = 0; e < 16; ++e) acc2[e] = bv;
    }

    for (int jq = 0; jq < 4; ++jq) {
        // ---- GEMM1 (swapped): D1[j][r], j-tile = jq*128 + wlo*32, r-tile = whi*32 ----
        f32x16 acc;
        int jb = jq * 128 + wlo * 32;
        #pragma unroll
        for (int reg = 0; reg < 16; ++reg)
            acc[reg] = b2[jb + (reg & 3) + 8 * (reg >> 2) + 4 * hl];
        uint h1base = (uint)((whi * 32 + l31) * 1024 + 16 * hl);
        #pragma unroll 4
        for (int ks = 0; ks < 32; ++ks) {
            bf16x8 af = *(const bf16x8*)(W2F + ((size_t)(ks * 16 + jq * 4 + wlo) * 64 + lane) * 8);
            bf16x8 bh = *(const bf16x8*)(H1 + swzA(h1base + ks * 32));
            acc = __builtin_amdgcn_mfma_f32_32x32x16_bf16(af, bh, acc, 0, 0, 0);
        }
        // h2q write: rows r = whi*32+l31, cols j' = wlo*32 + g*8 + 4*hl + 0..3
        {
            uint wbase = (uint)((whi * 32 + l31) * 256 + (wlo * 32 + 4 * hl) * 2);
            #pragma unroll
            for (int g = 0; g < 4; ++g) {
                uint p0 = pk2(fmaxf(acc[4 * g], 0.f), fmaxf(acc[4 * g + 1], 0.f));
                uint p1 = pk2(fmaxf(acc[4 * g + 2], 0.f), fmaxf(acc[4 * g + 3], 0.f));
                *(uint2*)(H2 + swzB(wbase + g * 16)) = make_uint2(p0, p1);
            }
        }
        __syncthreads();
        // ---- GEMM2 partial: D2[r][c] over k = j in [jq*128, +128) ----
        uint h2base = (uint)((whi * 32 + l31) * 256 + 16 * hl);
        #pragma unroll
        for (int k2 = 0; k2 < 8; ++k2) {
            bf16x8 ah = *(const bf16x8*)(H2 + swzB(h2base + k2 * 32));
            bf16x8 bw = *(const bf16x8*)(W3F + ((size_t)((jq * 8 + k2) * 4 + wlo) * 64 + lane) * 8);
            acc2 = __builtin_amdgcn_mfma_f32_32x32x16_bf16(ah, bw, acc2, 0, 0, 0);
        }
        __syncthreads();
    }

    // store: r = whi*32 + (reg&3)+8*(reg>>2)+4*hl, c = wlo*32 + l31
    {
        int c = wlo * 32 + l31;
        size_t rowbase = (size_t)b * TT + t0 + whi * 32 + 4 * hl;
        #pragma unroll
        for (int reg = 0; reg < 16; ++reg)
            out[(rowbase + (reg & 3) + 8 * (reg >> 2)) * D + c] = acc2[reg];
    }
}

extern "C" void kernel_launch(void* const* d_in, const int* in_sizes, int n_in,
                              void* d_out, int out_size, void* d_ws, size_t ws_size,
                              hipStream_t stream) {
    const float* timesteps = (const float*)d_in[0];
    const float* X        = (const float*)d_in[1];
    const float* M        = (const float*)d_in[2];
    const float* yts      = (const float*)d_in[3];
    const float* w_te     = (const float*)d_in[4];
    const float* b_te     = (const float*)d_in[5];
    const float* query    = (const float*)d_in[6];
    const float* W_q      = (const float*)d_in[7];
    const float* b_q      = (const float*)d_in[8];
    const float* W_k      = (const float*)d_in[9];
    const float* b_k      = (const float*)d_in[10];
    const float* W_o      = (const float*)d_in[11];
    const float* b_o      = (const float*)d_in[12];
    const float* W1       = (const float*)d_in[13];
    const float* b1       = (const float*)d_in[14];
    const float* W2       = (const float*)d_in[15];
    const float* b2       = (const float*)d_in[16];
    const float* W3       = (const float*)d_in[17];
    const float* b3       = (const float*)d_in[18];
    float* out = (float*)d_out;
    float* ws  = (float*)d_ws;

    float* qbuf   = ws + OFF_Q;
    float* vsin   = ws + OFF_VS;
    float* wA     = ws + OFF_WA;
    float* wB     = ws + OFF_WB;
    float* sbias  = ws + OFF_SB;
    float* Cvec   = ws + OFF_CV;
    float* pmax   = ws + OFF_PMAX;
    float* coeffs = ws + OFF_COEF;
    float* cvp    = ws + OFF_CVP;
    float* part2  = ws + OFF_P2;
    float* abuf   = ws + OFF_A;        // overlays part2 (dead after k_cred)
    float* part   = ws + OFF_PART;
    float* scores = ws + OFF_SC;
    ushort* W2F   = (ushort*)(ws + OFF_SC);     // overlays scores (dead after k_wsum)
    ushort* W3F   = W2F + (size_t)HID * HID;

    hipLaunchKernelGGL(k_q,      dim3(PP),          dim3(512), 0, stream, query, W_q, b_q, qbuf);
    hipLaunchKernelGGL(k_v,      dim3(HP),          dim3(512), 0, stream, W_k, b_k, qbuf, w_te, b_te, vsin, wA, wB, sbias);
    hipLaunchKernelGGL(k_cvp,    dim3(NH, 4),       dim3(256), 0, stream, W_o, cvp);
    hipLaunchKernelGGL(k_cvr,    dim3(1),           dim3(256), 0, stream, cvp, b_o, Cvec);
    hipLaunchKernelGGL(k_scores, dim3(BB * 8),      dim3(256), 0, stream, timesteps, w_te, b_te, vsin, wA, wB, sbias, scores, pmax);
    hipLaunchKernelGGL(k_wsum,   dim3(BB * CH),     dim3(256), 0, stream, scores, pmax, X, M, part);
    hipLaunchKernelGGL(k_cvt,    dim3(160),         dim3(256), 0, stream, W2, W3, W2F, W3F);
    hipLaunchKernelGGL(k_coefp,  dim3(BB, NH),      dim3(256), 0, stream, part, W_o, part2);
    hipLaunchKernelGGL(k_cred,   dim3(BB),          dim3(256), 0, stream, part2, Cvec, coeffs);
    hipLaunchKernelGGL(k_avec3,  dim3(BB),          dim3(512), 0, stream, coeffs, W1, b1, abuf);
    hipLaunchKernelGGL(k_mlp5,   dim3(BB, TT / 64), dim3(512), 0, stream, abuf, yts, W2F, b2, W3F, b3, out);
}

// Round 6
// 224.007 us; speedup vs baseline: 1.1678x; 1.1678x over previous
//
#include <hip/hip_runtime.h>
#include <math.h>

#define NH   8
#define PP   3
#define HP   24      // NH*PP
#define E    512
#define EK   64
#define D    128
#define LL   2048
#define BB   64
#define TT   1024
#define LAT  256
#define HID  512
#define CH   8       // l-chunks in weighted-sum pass
#define CL   256     // chunk length

typedef __attribute__((ext_vector_type(8))) short bf16x8;
typedef __attribute__((ext_vector_type(4))) float f32x4;
typedef __attribute__((ext_vector_type(16))) float f32x16;

// ---- workspace offsets (in floats) ----
#define OFF_Q      ((size_t)0)            // 1536
#define OFF_VS     ((size_t)2048)         // 1536 (vsin 24x64)
#define OFF_WA     ((size_t)4096)         // 24
#define OFF_WB     ((size_t)4128)         // 24
#define OFF_SB     ((size_t)4160)         // 24
#define OFF_CV     ((size_t)4224)         // 256
#define OFF_PMAX   ((size_t)4608)         // 12288 (64 x 8 x 24)
#define OFF_COEF   ((size_t)24576)        // 49152
#define OFF_CVP    ((size_t)73728)        // 8192 (cvec partials)
#define OFF_P2     ((size_t)81920)        // 393216 (part2; abuf overlays after k_cred)
#define OFF_A      ((size_t)81920)        // 98304  (abuf, overlays part2)
#define OFF_PART   ((size_t)475136)       // 3145728 (part)
#define OFF_SC     ((size_t)3620864)      // 3145728 (scores; W2F/W3F overlay after k_wsum)

__device__ inline ushort f2bf(float x) {
    union { float f; uint u; } v; v.f = x;
    uint r = v.u + 0x7fffu + ((v.u >> 16) & 1u);
    return (ushort)(r >> 16);
}
__device__ inline uint swz(uint a) { return a ^ (((a >> 8) & 7u) << 4); }   // 256B rows
__device__ inline uint pk2(float lo, float hi) {
    return (uint)f2bf(lo) | ((uint)f2bf(hi) << 16);
}
__device__ inline float h1f(float a0, float a1, float a2, float t) {
    return fmaxf(fmaf(t, fmaf(t, a2, a1), a0), 0.f);
}
// sigma: D1 row-slot -> j-within-tile (swap middle 4-pairs of each 16)
__device__ inline int sigma(int s) { return s ^ (((((s >> 2) ^ (s >> 3)) & 1)) ? 12 : 0); }

// K1: q[p][e] = query[p]@W_q + b_q   (batch-independent)
__global__ __launch_bounds__(512) void k_q(const float* __restrict__ query,
                                           const float* __restrict__ W_q,
                                           const float* __restrict__ b_q,
                                           float* __restrict__ qbuf) {
    int p = blockIdx.x, e = threadIdx.x;
    float acc = b_q[e];
    for (int i = 0; i < E; ++i) acc += query[p * E + i] * W_q[(size_t)i * E + e];
    qbuf[p * E + e] = acc;
}

// K2: per (hp): v[e] = (1/8)*sum_j W_k[e][h*64+j] q[p][..]; emit vsin (e%8==0 cols),
//     wA = sum v*w_te, wB = sum v*b_te, sbias.
__global__ __launch_bounds__(512) void k_v(const float* __restrict__ W_k,
                                           const float* __restrict__ b_k,
                                           const float* __restrict__ qbuf,
                                           const float* __restrict__ w_te,
                                           const float* __restrict__ b_te,
                                           float* __restrict__ vsin,
                                           float* __restrict__ wA,
                                           float* __restrict__ wB,
                                           float* __restrict__ sbias) {
    int hp = blockIdx.x;
    int h = hp / PP, p = hp % PP;
    int e = threadIdx.x;
    const float scale = 0.125f;  // 1/sqrt(64)
    float acc = 0.f;
    for (int j = 0; j < EK; ++j)
        acc += W_k[(size_t)e * E + h * EK + j] * qbuf[p * E + h * EK + j];
    float v = acc * scale;
    if ((e & 7) == 0) vsin[hp * 64 + (e >> 3)] = v;
    __shared__ float r1[512], r2[512];
    r1[e] = v * w_te[e];
    r2[e] = v * b_te[e];
    __syncthreads();
    for (int s = 256; s > 0; s >>= 1) {
        if (e < s) { r1[e] += r1[e + s]; r2[e] += r2[e + s]; }
        __syncthreads();
    }
    if (e == 0) {
        wA[hp] = r1[0];
        wB[hp] = r2[0];
        float sb = 0.f;
        for (int j = 0; j < EK; ++j) sb += b_k[h * EK + j] * qbuf[p * E + h * EK + j];
        sbias[hp] = sb * scale;
    }
}

// K2b: parallel Cvec partials: cvp[h*4+cc][o] = sum_{c in chunk} W_o[h*256+128+c][o]
__global__ __launch_bounds__(256) void k_cvp(const float* __restrict__ W_o,
                                             float* __restrict__ cvp) {
    int h = blockIdx.x, cc = blockIdx.y, o = threadIdx.x;
    float acc = 0.f;
    #pragma unroll 8
    for (int c = cc * 32; c < cc * 32 + 32; ++c)
        acc += W_o[(size_t)(h * 256 + 128 + c) * LAT + o];
    cvp[(h * 4 + cc) * LAT + o] = acc;
}

// K2c: Cvec[o] = b_o[o] + sum_32 cvp
__global__ __launch_bounds__(256) void k_cvr(const float* __restrict__ cvp,
                                             const float* __restrict__ b_o,
                                             float* __restrict__ Cvec) {
    int o = threadIdx.x;
    float acc = b_o[o];
    #pragma unroll
    for (int i = 0; i < 32; ++i) acc += cvp[i * LAT + o];
    Cvec[o] = acc;
}

// K3: scores[b][hp][l] = ts*wA[hp] + wB[hp] + sb[hp] + sum_j (sin(kj)-kj)*vsin[hp][j]
//     + per-(b,seg) partial max -> pmax
__global__ __launch_bounds__(256) void k_scores(const float* __restrict__ timesteps,
                                                const float* __restrict__ w_te,
                                                const float* __restrict__ b_te,
                                                const float* __restrict__ vsin,
                                                const float* __restrict__ wA,
                                                const float* __restrict__ wB,
                                                const float* __restrict__ sb,
                                                float* __restrict__ scores,
                                                float* __restrict__ pmax) {
    __shared__ float vs_s[HP * 64];   // 6 KB
    __shared__ float w8_s[64], b8_s[64];
    __shared__ float wA_s[HP], wB_s[HP], sb_s[HP];
    __shared__ float wmax_s[HP][4];
    int tid = threadIdx.x;
    for (int i = tid; i < HP * 64; i += 256) vs_s[i] = vsin[i];
    if (tid < 64) { w8_s[tid] = w_te[tid * 8]; b8_s[tid] = b_te[tid * 8]; }
    if (tid < HP) { wA_s[tid] = wA[tid]; wB_s[tid] = wB[tid]; sb_s[tid] = sb[tid]; }
    __syncthreads();

    int b = blockIdx.x >> 3, seg = blockIdx.x & 7;
    int l = seg * 256 + tid;
    float ts = timesteps[(size_t)b * LL + l];

    float dj[64];
    #pragma unroll
    for (int j = 0; j < 64; ++j) {
        float kj = fmaf(ts, w8_s[j], b8_s[j]);
        dj[j] = __sinf(kj) - kj;
    }

    int wid = tid >> 6, lane = tid & 63;
    for (int hp = 0; hp < HP; ++hp) {
        float acc = fmaf(ts, wA_s[hp], wB_s[hp]) + sb_s[hp];
        #pragma unroll
        for (int j0 = 0; j0 < 64; j0 += 4) {
            float4 v4 = *(const float4*)&vs_s[hp * 64 + j0];
            acc += dj[j0] * v4.x + dj[j0 + 1] * v4.y + dj[j0 + 2] * v4.z + dj[j0 + 3] * v4.w;
        }
        scores[((size_t)b * HP + hp) * LL + l] = acc;
        float m = acc;
        #pragma unroll
        for (int off = 32; off > 0; off >>= 1) m = fmaxf(m, __shfl_xor(m, off));
        if (lane == 0) wmax_s[hp][wid] = m;
    }
    __syncthreads();
    if (tid < HP)
        pmax[((size_t)b * 8 + seg) * HP + tid] =
            fmaxf(fmaxf(wmax_s[tid][0], wmax_s[tid][1]), fmaxf(wmax_s[tid][2], wmax_s[tid][3]));
}

// K5: per-chunk partial weighted sums: part[b][ch][hp][0:128]=num, [128:256]=den
__global__ __launch_bounds__(256) void k_wsum(const float* __restrict__ scores,
                                              const float* __restrict__ pmax,
                                              const float* __restrict__ X,
                                              const float* __restrict__ M,
                                              float* __restrict__ part) {
    int b = blockIdx.x / CH, ch = blockIdx.x % CH;
    int l0 = ch * CL, tid = threadIdx.x;
    __shared__ float m_s[HP];
    __shared__ float w_s[HP][CL];   // 24 KB
    if (tid < HP) {
        float m = -INFINITY;
        for (int s = 0; s < 8; ++s) m = fmaxf(m, pmax[((size_t)b * 8 + s) * HP + tid]);
        m_s[tid] = m;
    }
    __syncthreads();
    for (int i = tid; i < HP * CL; i += 256) {
        int hp = i / CL, lc = i % CL;
        w_s[hp][lc] = __expf(scores[((size_t)b * HP + hp) * LL + l0 + lc] - m_s[hp]);
    }
    __syncthreads();

    int c = tid & 127;
    int hh = tid >> 7;   // hp half: 12*hh .. 12*hh+11
    float accn[12], accd[12];
    #pragma unroll
    for (int i = 0; i < 12; ++i) { accn[i] = 0.f; accd[i] = 0.f; }

    for (int lc = 0; lc < CL; lc += 4) {
        float mv[4], xv[4];
        #pragma unroll
        for (int j = 0; j < 4; ++j) {
            size_t l = (size_t)b * LL + l0 + lc + j;
            mv[j] = M[l * D + c];
            xv[j] = X[l * D + c] * mv[j];
        }
        #pragma unroll
        for (int i = 0; i < 12; ++i) {
            const float4 w4 = *(const float4*)&w_s[12 * hh + i][lc];
            accn[i] += w4.x * xv[0] + w4.y * xv[1] + w4.z * xv[2] + w4.w * xv[3];
            accd[i] += w4.x * mv[0] + w4.y * mv[1] + w4.z * mv[2] + w4.w * mv[3];
        }
    }
    #pragma unroll
    for (int i = 0; i < 12; ++i) {
        int hp = 12 * hh + i;
        size_t base = ((size_t)(b * CH + ch) * HP + hp) * 256;
        part[base + c]       = accn[i];
        part[base + 128 + c] = accd[i];
    }
}

// K6a: per (b,h): ratio = num/den (with inline chunk reduce), partial W_o matmul
__global__ __launch_bounds__(256) void k_coefp(const float* __restrict__ part,
                                               const float* __restrict__ W_o,
                                               float* __restrict__ part2) {
    int b = blockIdx.x, h = blockIdx.y;
    int tid = threadIdx.x;
    __shared__ float ratio[PP][D];   // 1.5 KB
    for (int ii = tid; ii < PP * D; ii += 256) {
        int p = ii >> 7, c = ii & 127;
        int hp = h * PP + p;
        float n = 0.f, d = 0.f;
        for (int ch = 0; ch < CH; ++ch) {
            size_t base = ((size_t)(b * CH + ch) * HP + hp) * 256;
            n += part[base + c];
            d += part[base + 128 + c];
        }
        ratio[p][c] = n / d;
    }
    __syncthreads();
    int o = tid;
    float a0 = 0.f, a1 = 0.f, a2 = 0.f;
    #pragma unroll 4
    for (int c = 0; c < D; ++c) {
        float w = W_o[(size_t)(h * 256 + c) * LAT + o];
        a0 = fmaf(ratio[0][c], w, a0);
        a1 = fmaf(ratio[1][c], w, a1);
        a2 = fmaf(ratio[2][c], w, a2);
    }
    size_t base = (((size_t)b * NH + h) * PP) * LAT + o;
    part2[base]           = a0;
    part2[base + LAT]     = a1;
    part2[base + 2 * LAT] = a2;
}

// K6b: coeffs[b][p][o] = Cvec[o] + sum_h part2[b][h][p][o]
__global__ __launch_bounds__(256) void k_cred(const float* __restrict__ part2,
                                              const float* __restrict__ Cvec,
                                              float* __restrict__ coeffs) {
    int b = blockIdx.x, o = threadIdx.x;
    float cv = Cvec[o];
    for (int p = 0; p < PP; ++p) {
        float s = cv;
        for (int h = 0; h < NH; ++h)
            s += part2[(((size_t)b * NH + h) * PP + p) * LAT + o];
        coeffs[((size_t)b * PP + p) * LAT + o] = s;
    }
}

// K5c: build 32x32x16 fragment-major bf16 weights.
// W2F frag F = ks*16+JT: lane l elem e = W2[ks*16+8*(l>>5)+e][JT*32 + sigma(l&31)]
//   (sigma-permuted columns so GEMM1's D1 rows land in A-fragment order for GEMM2)
// W3F frag F2 = KT*4+CT:  lane l elem e = W3[KT*16+8*(l>>5)+e][CT*32+(l&31)]
__global__ __launch_bounds__(256) void k_cvt(const float* __restrict__ W2,
                                             const float* __restrict__ W3,
                                             ushort* __restrict__ W2F,
                                             ushort* __restrict__ W3F) {
    int gid = blockIdx.x * 256 + threadIdx.x;
    int l = gid & 63;
    int kb = 8 * (l >> 5);
    int cb = l & 31;
    if (gid < 32768) {
        int F = gid >> 6;           // 0..511
        int JT = F & 15, ks = F >> 4;
        int cbp = sigma(cb);
        int k0 = ks * 16 + kb, j = JT * 32 + cbp;
        #pragma unroll
        for (int e = 0; e < 8; ++e)
            W2F[(size_t)gid * 8 + e] = f2bf(W2[(size_t)(k0 + e) * HID + j]);
    } else if (gid < 40960) {
        int g2 = gid - 32768;       // 0..8191
        int F2 = g2 >> 6;           // 0..127
        int CT = F2 & 3, KT = F2 >> 2;
        int k0 = KT * 16 + kb, c = CT * 32 + cb;
        #pragma unroll
        for (int e = 0; e < 8; ++e)
            W3F[(size_t)g2 * 8 + e] = f2bf(W3[(size_t)(k0 + e) * D + c]);
    }
}

// K7: a[b][i][j] = coeffs[b][i]@W1[:,j] (+ b1 for i==0); one block per b reads W1 once
__global__ __launch_bounds__(512) void k_avec3(const float* __restrict__ coeffs,
                                               const float* __restrict__ W1,
                                               const float* __restrict__ b1,
                                               float* __restrict__ abuf) {
    int b = blockIdx.x, j = threadIdx.x;
    const float* cf = coeffs + (size_t)b * PP * LAT;
    float a0 = b1[j], a1 = 0.f, a2 = 0.f;
    #pragma unroll 4
    for (int k = 0; k < LAT; ++k) {
        float w = W1[(size_t)k * HID + j];
        a0 = fmaf(cf[k], w, a0);
        a1 = fmaf(cf[LAT + k], w, a1);
        a2 = fmaf(cf[2 * LAT + k], w, a2);
    }
    abuf[(size_t)b * 3 * HID + j] = a0;
    abuf[(size_t)b * 3 * HID + HID + j] = a1;
    abuf[(size_t)b * 3 * HID + 2 * HID + j] = a2;
}

// K8: fused MFMA MLP v6. 128 rows/block, 512 thr (8 waves = 4 rt x 2 jh).
// H1: [4 kp][128 r][128 kk] bf16, 256B rows, swz ^=((a>>8)&7)<<4. Staged once (contiguous
// per-thread writes = conflict-free). GEMM1 operand-swapped with sigma-permuted W2F so
// GEMM2's A-fragments are the GEMM1 accumulators verbatim (no H2, no shuffles).
// Cross-jh partial sums reduced through LDS f32 (stride-1).
__global__ __launch_bounds__(512, 2) void k_mlp6(const float* __restrict__ abuf,
                                                 const float* __restrict__ yts,
                                                 const ushort* __restrict__ W2F,
                                                 const float* __restrict__ b2,
                                                 const ushort* __restrict__ W3F,
                                                 const float* __restrict__ b3,
                                                 float* __restrict__ out) {
    __shared__ char lds[131072];   // H1 (128KB); first 64KB reused as f32 reduce buffer
    int b = blockIdx.x, t0 = blockIdx.y * 128, tid = threadIdx.x;
    const float* a0p = abuf + (size_t)b * 3 * HID;
    const float* a1p = a0p + HID;
    const float* a2p = a1p + HID;

    // phase A: thread tid owns one contiguous 256B row-panel: kp = tid>>7, r = tid&127
    {
        int r = tid & 127, kp = tid >> 7;
        float t = yts[(size_t)b * TT + t0 + r];
        uint base = (uint)tid * 256;
        #pragma unroll
        for (int i = 0; i < 8; ++i) {
            int k = kp * 128 + i * 16;
            float4 x0a = *(const float4*)(a0p + k),     x0b = *(const float4*)(a0p + k + 4);
            float4 x0c = *(const float4*)(a0p + k + 8), x0d = *(const float4*)(a0p + k + 12);
            float4 x1a = *(const float4*)(a1p + k),     x1b = *(const float4*)(a1p + k + 4);
            float4 x1c = *(const float4*)(a1p + k + 8), x1d = *(const float4*)(a1p + k + 12);
            float4 x2a = *(const float4*)(a2p + k),     x2b = *(const float4*)(a2p + k + 4);
            float4 x2c = *(const float4*)(a2p + k + 8), x2d = *(const float4*)(a2p + k + 12);
            uint4 lo, hi;
            lo.x = pk2(h1f(x0a.x, x1a.x, x2a.x, t), h1f(x0a.y, x1a.y, x2a.y, t));
            lo.y = pk2(h1f(x0a.z, x1a.z, x2a.z, t), h1f(x0a.w, x1a.w, x2a.w, t));
            lo.z = pk2(h1f(x0b.x, x1b.x, x2b.x, t), h1f(x0b.y, x1b.y, x2b.y, t));
            lo.w = pk2(h1f(x0b.z, x1b.z, x2b.z, t), h1f(x0b.w, x1b.w, x2b.w, t));
            hi.x = pk2(h1f(x0c.x, x1c.x, x2c.x, t), h1f(x0c.y, x1c.y, x2c.y, t));
            hi.y = pk2(h1f(x0c.z, x1c.z, x2c.z, t), h1f(x0c.w, x1c.w, x2c.w, t));
            hi.z = pk2(h1f(x0d.x, x1d.x, x2d.x, t), h1f(x0d.y, x1d.y, x2d.y, t));
            hi.w = pk2(h1f(x0d.z, x1d.z, x2d.z, t), h1f(x0d.w, x1d.w, x2d.w, t));
            *(uint4*)(lds + swz(base + i * 32))      = lo;
            *(uint4*)(lds + swz(base + i * 32 + 16)) = hi;
        }
    }
    __syncthreads();

    int lane = tid & 63, w = tid >> 6;
    int l31 = lane & 31, hl = lane >> 5;
    int rt = w & 3, jh = w >> 2;
    int r = rt * 32 + l31;

    f32x16 acc2[4];
    #pragma unroll
    for (int ct = 0; ct < 4; ++ct)
        #pragma unroll
        for (int e = 0; e < 16; ++e) acc2[ct][e] = 0.f;

    #pragma unroll
    for (int p = 0; p < 2; ++p) {
        // ---- GEMM1 (swapped): D1[j][r] for j-tiles jh*256 + p*128 + jti*32 ----
        f32x16 acc[4];
        #pragma unroll
        for (int jti = 0; jti < 4; ++jti) {
            int jT = jh * 256 + p * 128 + jti * 32;
            #pragma unroll
            for (int reg = 0; reg < 16; ++reg) {
                int slot = (reg & 3) + 8 * (reg >> 2) + 4 * hl;
                acc[jti][reg] = b2[jT + sigma(slot)];
            }
        }
        #pragma unroll 4
        for (int ks = 0; ks < 32; ++ks) {
            uint byte = (uint)((ks >> 3) * 32768 + r * 256 + (ks & 7) * 32 + hl * 16);
            bf16x8 bh = *(const bf16x8*)(lds + swz(byte));
            #pragma unroll
            for (int jti = 0; jti < 4; ++jti) {
                int JT = jh * 8 + p * 4 + jti;
                bf16x8 af = *(const bf16x8*)(W2F + ((size_t)(ks * 16 + JT) * 64 + lane) * 8);
                acc[jti] = __builtin_amdgcn_mfma_f32_32x32x16_bf16(af, bh, acc[jti], 0, 0, 0);
            }
        }
        // ---- GEMM2 partials: h2 frags = relu(acc) regs in-order (sigma magic) ----
        #pragma unroll
        for (int jti = 0; jti < 4; ++jti) {
            int jsbase = jh * 16 + p * 8 + jti * 2;
            #pragma unroll
            for (int s = 0; s < 2; ++s) {
                uint4 uu;
                uu.x = pk2(fmaxf(acc[jti][8 * s + 0], 0.f), fmaxf(acc[jti][8 * s + 1], 0.f));
                uu.y = pk2(fmaxf(acc[jti][8 * s + 2], 0.f), fmaxf(acc[jti][8 * s + 3], 0.f));
                uu.z = pk2(fmaxf(acc[jti][8 * s + 4], 0.f), fmaxf(acc[jti][8 * s + 5], 0.f));
                uu.w = pk2(fmaxf(acc[jti][8 * s + 6], 0.f), fmaxf(acc[jti][8 * s + 7], 0.f));
                bf16x8 afrag = *(bf16x8*)&uu;
                #pragma unroll
                for (int ct = 0; ct < 4; ++ct) {
                    bf16x8 bw = *(const bf16x8*)(W3F + ((size_t)((jsbase + s) * 4 + ct) * 64 + lane) * 8);
                    acc2[ct] = __builtin_amdgcn_mfma_f32_32x32x16_bf16(afrag, bw, acc2[ct], 0, 0, 0);
                }
            }
        }
    }
    __syncthreads();   // all H1 reads done; reuse LDS as f32 reduce buffer

    float* red = (float*)lds;
    if (jh == 1) {
        #pragma unroll
        for (int ct = 0; ct < 4; ++ct)
            #pragma unroll
            for (int reg = 0; reg < 16; ++reg) {
                int rloc = (reg & 3) + 8 * (reg >> 2) + 4 * hl;
                red[rt * 4096 + rloc * 128 + ct * 32 + l31] = acc2[ct][reg];
            }
    }
    __syncthreads();
    if (jh == 0) {
        #pragma unroll
        for (int ct = 0; ct < 4; ++ct) {
            float bv = b3[ct * 32 + l31];
            #pragma unroll
            for (int reg = 0; reg < 16; ++reg) {
                int rloc = (reg & 3) + 8 * (reg >> 2) + 4 * hl;
                float v = acc2[ct][reg] + red[rt * 4096 + rloc * 128 + ct * 32 + l31] + bv;
                out[((size_t)b * TT + t0 + rt * 32 + rloc) * D + ct * 32 + l31] = v;
            }
        }
    }
}

extern "C" void kernel_launch(void* const* d_in, const int* in_sizes, int n_in,
                              void* d_out, int out_size, void* d_ws, size_t ws_size,
                              hipStream_t stream) {
    const float* timesteps = (const float*)d_in[0];
    const float* X        = (const float*)d_in[1];
    const float* M        = (const float*)d_in[2];
    const float* yts      = (const float*)d_in[3];
    const float* w_te     = (const float*)d_in[4];
    const float* b_te     = (const float*)d_in[5];
    const float* query    = (const float*)d_in[6];
    const float* W_q      = (const float*)d_in[7];
    const float* b_q      = (const float*)d_in[8];
    const float* W_k      = (const float*)d_in[9];
    const float* b_k      = (const float*)d_in[10];
    const float* W_o      = (const float*)d_in[11];
    const float* b_o      = (const float*)d_in[12];
    const float* W1       = (const float*)d_in[13];
    const float* b1       = (const float*)d_in[14];
    const float* W2       = (const float*)d_in[15];
    const float* b2       = (const float*)d_in[16];
    const float* W3       = (const float*)d_in[17];
    const float* b3       = (const float*)d_in[18];
    float* out = (float*)d_out;
    float* ws  = (float*)d_ws;

    float* qbuf   = ws + OFF_Q;
    float* vsin   = ws + OFF_VS;
    float* wA     = ws + OFF_WA;
    float* wB     = ws + OFF_WB;
    float* sbias  = ws + OFF_SB;
    float* Cvec   = ws + OFF_CV;
    float* pmax   = ws + OFF_PMAX;
    float* coeffs = ws + OFF_COEF;
    float* cvp    = ws + OFF_CVP;
    float* part2  = ws + OFF_P2;
    float* abuf   = ws + OFF_A;        // overlays part2 (dead after k_cred)
    float* part   = ws + OFF_PART;
    float* scores = ws + OFF_SC;
    ushort* W2F   = (ushort*)(ws + OFF_SC);     // overlays scores (dead after k_wsum)
    ushort* W3F   = W2F + (size_t)HID * HID;

    hipLaunchKernelGGL(k_q,      dim3(PP),          dim3(512), 0, stream, query, W_q, b_q, qbuf);
    hipLaunchKernelGGL(k_v,      dim3(HP),          dim3(512), 0, stream, W_k, b_k, qbuf, w_te, b_te, vsin, wA, wB, sbias);
    hipLaunchKernelGGL(k_cvp,    dim3(NH, 4),       dim3(256), 0, stream, W_o, cvp);
    hipLaunchKernelGGL(k_cvr,    dim3(1),           dim3(256), 0, stream, cvp, b_o, Cvec);
    hipLaunchKernelGGL(k_scores, dim3(BB * 8),      dim3(256), 0, stream, timesteps, w_te, b_te, vsin, wA, wB, sbias, scores, pmax);
    hipLaunchKernelGGL(k_wsum,   dim3(BB * CH),     dim3(256), 0, stream, scores, pmax, X, M, part);
    hipLaunchKernelGGL(k_cvt,    dim3(160),         dim3(256), 0, stream, W2, W3, W2F, W3F);
    hipLaunchKernelGGL(k_coefp,  dim3(BB, NH),      dim3(256), 0, stream, part, W_o, part2);
    hipLaunchKernelGGL(k_cred,   dim3(BB),          dim3(256), 0, stream, part2, Cvec, coeffs);
    hipLaunchKernelGGL(k_avec3,  dim3(BB),          dim3(512), 0, stream, coeffs, W1, b1, abuf);
    hipLaunchKernelGGL(k_mlp6,   dim3(BB, TT / 128), dim3(512), 0, stream, abuf, yts, W2F, b2, W3F, b3, out);
}